// Round 10
// baseline (102.358 us; speedup 1.0000x reference)
//
#include <hip/hip_runtime.h>
#include <hip/hip_bf16.h>

typedef __attribute__((ext_vector_type(8))) short s16x8;
typedef __attribute__((ext_vector_type(4))) float f32x4;
typedef __attribute__((ext_vector_type(8))) unsigned short u16x8;
typedef __attribute__((ext_vector_type(4))) unsigned short u16x4;

static __device__ __forceinline__ unsigned short f2bf(float f) {
  unsigned int u = __float_as_uint(f);
  unsigned int r = u + 0x7fffu + ((u >> 16) & 1u);
  return (unsigned short)(r >> 16);
}
static __device__ __forceinline__ float bf2f(unsigned short s) {
  return __uint_as_float(((unsigned int)s) << 16);
}

static __device__ __forceinline__ void gload16(const void* g, void* l) {
  __builtin_amdgcn_global_load_lds(
      (const __attribute__((address_space(1))) unsigned int*)g,
      (__attribute__((address_space(3))) unsigned int*)l, 16, 0, 0);
}

// ---------------- fused pre-pass ----------------
// blocks [0,3584): patchify strip -> xbf (bf16) + per-(bc,hp) partial sums
// blocks [3584,3776): proj_w fp32 -> bf16
// blocks [3776,4352): ctx_w transpose -> cwT
// strip stride 280 shorts (560B = 140 dw = 12 mod 32, gcd 4 -> bank period 8
// over 14 wp -> 2-way scatter conflicts (free); 560 = 35*16 keeps 16B align).
__global__ __launch_bounds__(256) void k_mega(const float* __restrict__ x,
                                              unsigned short* __restrict__ xbf,
                                              float* __restrict__ avg3,
                                              const float* __restrict__ pw,
                                              unsigned short* __restrict__ pwbf,
                                              const float* __restrict__ cw,
                                              float* __restrict__ cwT) {
  __shared__ __align__(16) char smem[14 * 280 * 2];  // 7840 B
  int b = blockIdx.x, t = threadIdx.x;
  if (b < 3584) {
    unsigned short* strip = (unsigned short*)smem;
    int bc = b / 14, hp = b - bc * 14;
    const float* img = x + ((size_t)bc * 224 + hp * 16) * 224;
    for (int idx = t; idx < 896; idx += 256) {
      int row = idx / 56, c4 = idx - row * 56;
      float4 v = reinterpret_cast<const float4*>(img + (size_t)row * 224)[c4];
      int wp = c4 >> 2, q0 = (c4 & 3) << 2;
      u16x4 pk = { f2bf(v.x), f2bf(v.y), f2bf(v.z), f2bf(v.w) };
      *(u16x4*)&strip[wp * 280 + row * 16 + q0] = pk;
    }
    __syncthreads();
    float acc = 0.f;
#pragma unroll
    for (int wp = 0; wp < 14; ++wp) acc += bf2f(strip[wp * 280 + t]);
    avg3[((size_t)bc * 14 + hp) * 256 + t] = acc;
    unsigned short* orow = xbf + ((size_t)bc * 196 + hp * 14) * 256;
    for (int i = t; i < 448; i += 256) {
      int patch = i >> 5, rem = i & 31;
      u16x8 v = *(const u16x8*)&strip[patch * 280 + (rem >> 1) * 16 + (rem & 1) * 8];
      *(u16x8*)(orow + i * 8) = v;
    }
  } else if (b < 3776) {
    int i = (b - 3584) * 256 + t;
    float4 v = reinterpret_cast<const float4*>(pw)[i];
    u16x4 pk = { f2bf(v.x), f2bf(v.y), f2bf(v.z), f2bf(v.w) };
    reinterpret_cast<u16x4*>(pwbf)[i] = pk;
  } else {
    float (*tile)[33] = (float(*)[33])smem;  // 4224 B
    int bid2 = b - 3776;
    int bx = bid2 % 24, by = bid2 / 24;
    int tx = t & 31, ty = t >> 5;
#pragma unroll
    for (int k = 0; k < 4; ++k)
      tile[ty + 8 * k][tx] = cw[(size_t)(by * 32 + ty + 8 * k) * 768 + bx * 32 + tx];
    __syncthreads();
#pragma unroll
    for (int k = 0; k < 4; ++k)
      cwT[(size_t)(bx * 32 + ty + 8 * k) * 768 + by * 32 + tx] = tile[tx][ty + 8 * k];
  }
}

// ---------------- fused segment-mean + means projection ----------------
// grid 32 (one block per segment), 768 threads.
// Phase A: sp[k] = (sum over bc: seg[bc]==s, hp of avg3) / (196*max(cnt,1))
//          3 bc-slices (85/85/86) x 256 k, LDS reduce.
// Phase B: means[s][e] = dot(sp, pw[e]) + pb[e], e = t (pw L2-warm from mega).
__global__ __launch_bounds__(768) void k_sm(const float* __restrict__ avg3,
                                            const int* __restrict__ seg,
                                            const float* __restrict__ pw,
                                            const float* __restrict__ pb,
                                            float* __restrict__ means) {
  __shared__ float red[3][256];
  __shared__ int rcnt[3];
  __shared__ int ssg[256];
  __shared__ float spl[256];
  int s = blockIdx.x, t = threadIdx.x;
  if (t < 256) ssg[t] = seg[t];
  __syncthreads();
  int k = t & 255, slice = t >> 8;
  int b0 = slice * 85, b1 = (slice == 2) ? 256 : b0 + 85;
  float sum = 0.f; int cnt = 0;
  for (int bc = b0; bc < b1; ++bc) {
    if (ssg[bc] == s) {
      ++cnt;
      const float* row = avg3 + (size_t)bc * 14 * 256 + k;
#pragma unroll
      for (int hp = 0; hp < 14; ++hp) sum += row[hp * 256];
    }
  }
  red[slice][k] = sum;
  if (k == 0) rcnt[slice] = cnt;
  __syncthreads();
  if (t < 256) {
    int c = rcnt[0] + rcnt[1] + rcnt[2];
    spl[t] = (red[0][t] + red[1][t] + red[2][t]) / (196.0f * (float)(c > 0 ? c : 1));
  }
  __syncthreads();
  const float4* w = reinterpret_cast<const float4*>(pw + (size_t)t * 256);
  float a = 0.f;
#pragma unroll 8
  for (int j = 0; j < 64; ++j) {
    float4 v = w[j];
    a += v.x * spl[j * 4] + v.y * spl[j * 4 + 1] + v.z * spl[j * 4 + 2] + v.w * spl[j * 4 + 3];
  }
  means[s * 768 + t] = a + pb[t];
}

// addv[s][e] = means[s] . cwT[:,e] + cb[e] + pb[e]
__global__ __launch_bounds__(256) void k_ctx2(const float* __restrict__ means,
                                              const float* __restrict__ cwT,
                                              const float* __restrict__ cb,
                                              const float* __restrict__ pb,
                                              float* __restrict__ addv) {
  __shared__ float mn[768];
  __shared__ float red[8][32];
  int s = blockIdx.x & 31, e0 = (blockIdx.x >> 5) << 5;
  int t = threadIdx.x;
  int e = t & 31, fsl = t >> 5;
  mn[t] = means[s * 768 + t];
  mn[t + 256] = means[s * 768 + 256 + t];
  mn[t + 512] = means[s * 768 + 512 + t];
  __syncthreads();
  const float* col = cwT + (size_t)fsl * 96 * 768 + e0 + e;
  float a = 0.f;
#pragma unroll 8
  for (int j = 0; j < 96; ++j) a += mn[fsl * 96 + j] * col[(size_t)j * 768];
  red[fsl][e] = a;
  __syncthreads();
  if (t < 32) {
    float tot = 0.f;
#pragma unroll
    for (int j = 0; j < 8; ++j) tot += red[j][t];
    addv[s * 768 + e0 + t] = tot + cb[e0 + t] + pb[e0 + t];
  }
}

// ---------------- main GEMM (round-8 winner, unchanged) ----------------
// BM=128, BN=256, BK=64, 8 waves (2m x 4n), single-buffer, 2 barriers/tile.
// Swapped-operand MFMA -> lane holds 4 consecutive n -> dwordx4 epilogue.
__global__ __launch_bounds__(512) void k_gemm(
    const unsigned short* __restrict__ xbf, const unsigned short* __restrict__ wbf,
    const float* __restrict__ addv, const int* __restrict__ seg,
    float* __restrict__ out) {
  __shared__ __align__(16) unsigned short Al[128 * 64];  // 16 KB
  __shared__ __align__(16) unsigned short Bl[256 * 64];  // 32 KB

  // grid 1176 = 8 XCD x (49 mb x 3 nb)
  int bid = blockIdx.x;
  int xcd = bid & 7, local = bid >> 3;
  int mb = xcd * 49 + local / 3;
  int nb = local - (local / 3) * 3;
  int m0 = mb << 7, n0 = nb << 8;

  int t = threadIdx.x;
  int wave = t >> 6, lane = t & 63;
  int wm = (wave >> 2) << 6, wn = (wave & 3) << 6;
  int lr = lane & 15, hi = lane >> 4;
  int axor = (lr & 7) << 4;

  int swz = (((lane & 7) ^ ((lane >> 3) & 7)) << 4);
  const char* abase = (const char*)xbf + (size_t)(m0 + wave * 16 + (lane >> 3)) * 512 + swz;
  const char* bbase = (const char*)wbf + (size_t)(n0 + wave * 32 + (lane >> 3)) * 512 + swz;
  char* adst = (char*)Al + wave * 2048;
  char* bdst = (char*)Bl + wave * 4096;
  const char* Alc = (const char*)Al;
  const char* Blc = (const char*)Bl;

  f32x4 acc[4][4] = {};

  for (int kt = 0; kt < 4; ++kt) {
    __syncthreads();  // previous tile consumed
#pragma unroll
    for (int i = 0; i < 2; ++i)
      gload16(abase + kt * 128 + i * 4096, adst + i * 1024);
#pragma unroll
    for (int i = 0; i < 4; ++i)
      gload16(bbase + kt * 128 + i * 4096, bdst + i * 1024);
    __syncthreads();  // drains vmcnt + lgkm
#pragma unroll
    for (int kk = 0; kk < 2; ++kk) {
      s16x8 af[4], bv[4];
      int koff = kk * 64 + hi * 16;
#pragma unroll
      for (int i = 0; i < 4; ++i)
        af[i] = *(const s16x8*)(Alc + (wm + i * 16 + lr) * 128 + (koff ^ axor));
#pragma unroll
      for (int j = 0; j < 4; ++j)
        bv[j] = *(const s16x8*)(Blc + (wn + j * 16 + lr) * 128 + (koff ^ axor));
#pragma unroll
      for (int i = 0; i < 4; ++i)
#pragma unroll
        for (int j = 0; j < 4; ++j)
          acc[i][j] = __builtin_amdgcn_mfma_f32_16x16x32_bf16(bv[j], af[i], acc[i][j], 0, 0, 0);
    }
  }

#pragma unroll
  for (int i = 0; i < 4; ++i) {
    int M = m0 + wm + i * 16 + lr;
    int sgi = seg[M / 196];
    const float* av = addv + (size_t)sgi * 768 + n0 + wn + hi * 4;
    float* orow = out + (size_t)M * 768 + n0 + wn + hi * 4;
#pragma unroll
    for (int j = 0; j < 4; ++j) {
      f32x4 a4 = *(const f32x4*)(av + j * 16);
      f32x4 v = acc[i][j];
      v.x += a4.x; v.y += a4.y; v.z += a4.z; v.w += a4.w;
      *(f32x4*)(orow + j * 16) = v;
    }
  }
}

// ---------------- fallback path (if ws too small) ----------------
__global__ void k_cvt_fb(const float* __restrict__ in, unsigned short* __restrict__ o) {
  int i = blockIdx.x * 256 + threadIdx.x;
  float4 v = reinterpret_cast<const float4*>(in)[i];
  u16x4 pk = { f2bf(v.x), f2bf(v.y), f2bf(v.z), f2bf(v.w) };
  reinterpret_cast<u16x4*>(o)[i] = pk;
}

__global__ void k_transpose_fb(const float* __restrict__ in, float* __restrict__ out) {
  __shared__ float tile[32][33];
  int bx = blockIdx.x % 24, by = blockIdx.x / 24;
  int tx = threadIdx.x & 31, ty = threadIdx.x >> 5;
#pragma unroll
  for (int k = 0; k < 4; ++k)
    tile[ty + 8 * k][tx] = in[(size_t)(by * 32 + ty + 8 * k) * 768 + bx * 32 + tx];
  __syncthreads();
#pragma unroll
  for (int k = 0; k < 4; ++k)
    out[(size_t)(bx * 32 + ty + 8 * k) * 768 + by * 32 + tx] = tile[tx][ty + 8 * k];
}

__global__ void k_avgpatch_fb(const float* __restrict__ x, float* __restrict__ avg) {
  int bc = blockIdx.x;
  int k = threadIdx.x;
  int p = k >> 4, q = k & 15;
  const float* base = x + (size_t)bc * 224 * 224;
  float s = 0.f;
  for (int hp = 0; hp < 14; ++hp) {
    const float* row = base + (hp * 16 + p) * 224 + q;
#pragma unroll
    for (int wp = 0; wp < 14; ++wp) s += row[wp * 16];
  }
  avg[bc * 256 + k] = s * (1.0f / 196.0f);
}

__global__ __launch_bounds__(768) void k_chain_fb(const float* __restrict__ avg,
                                                  const int* __restrict__ seg,
                                                  const float* __restrict__ pw,
                                                  const float* __restrict__ pb,
                                                  const float* __restrict__ cwT,
                                                  const float* __restrict__ cb,
                                                  float* __restrict__ addv) {
  __shared__ float sp[256];
  __shared__ float mn[768];
  __shared__ int ssg[256];
  int s = blockIdx.x, t = threadIdx.x;
  if (t < 256) ssg[t] = seg[t];
  __syncthreads();
  if (t < 256) {
    float sum = 0.f; int c = 0;
    for (int bc = 0; bc < 256; ++bc)
      if (ssg[bc] == s) { sum += avg[bc * 256 + t]; ++c; }
    sp[t] = sum / (float)(c > 0 ? c : 1);
  }
  __syncthreads();
  {
    const float4* w = reinterpret_cast<const float4*>(pw + (size_t)t * 256);
    float a = 0.f;
#pragma unroll 8
    for (int k = 0; k < 64; ++k) {
      float4 v = w[k];
      a += v.x * sp[k * 4] + v.y * sp[k * 4 + 1] + v.z * sp[k * 4 + 2] + v.w * sp[k * 4 + 3];
    }
    mn[t] = a + pb[t];
  }
  __syncthreads();
  float a2 = 0.f;
#pragma unroll 8
  for (int f = 0; f < 768; ++f) a2 += mn[f] * cwT[(size_t)f * 768 + t];
  addv[s * 768 + t] = a2 + cb[t] + pb[t];
}

__global__ __launch_bounds__(256) void k_gemm_fb(
    const float* __restrict__ x, const unsigned short* __restrict__ wbf,
    const float* __restrict__ addv, const int* __restrict__ seg,
    float* __restrict__ out) {
  __shared__ unsigned short Al[128][40];
  __shared__ unsigned short Bl[128][40];
  int bid = blockIdx.x;
  int xcd = bid & 7, local = bid >> 3;
  int mb = xcd * 49 + local / 6;
  int nb = local - (local / 6) * 6;
  int m0 = mb << 7, n0 = nb << 7;
  int t = threadIdx.x;
  int wave = t >> 6, lane = t & 63;
  int wm = (wave >> 1) << 6, wn = (wave & 1) << 6;
  int lr = lane & 15, lk = (lane >> 4) << 3;
  int mstage = m0 + (t >> 1);
  int halfA = t & 1;
  int bc = mstage / 196;
  int pij = mstage - bc * 196;
  int hp = pij / 14;
  int wp = pij - hp * 14;
  const float* xbase = x + ((size_t)bc * 224 + hp * 16 + halfA) * 224 + wp * 16;
  const unsigned short* bsrc = wbf + (size_t)(n0 + (t >> 1)) * 256 + halfA * 16;
  unsigned short* adst = &Al[t >> 1][halfA * 16];
  unsigned short* bdst = &Bl[t >> 1][halfA * 16];
  f32x4 acc[4][4] = {};
  for (int ks = 0; ks < 8; ++ks) {
    __syncthreads();
    *(u16x8*)bdst       = *(const u16x8*)(bsrc + ks * 32);
    *(u16x8*)(bdst + 8) = *(const u16x8*)(bsrc + ks * 32 + 8);
    {
      const float4* src = reinterpret_cast<const float4*>(xbase + ks * 448);
      float4 v0 = src[0], v1 = src[1], v2 = src[2], v3 = src[3];
      u16x8 p0 = { f2bf(v0.x), f2bf(v0.y), f2bf(v0.z), f2bf(v0.w),
                   f2bf(v1.x), f2bf(v1.y), f2bf(v1.z), f2bf(v1.w) };
      u16x8 p1 = { f2bf(v2.x), f2bf(v2.y), f2bf(v2.z), f2bf(v2.w),
                   f2bf(v3.x), f2bf(v3.y), f2bf(v3.z), f2bf(v3.w) };
      *(u16x8*)adst = p0;
      *(u16x8*)(adst + 8) = p1;
    }
    __syncthreads();
    s16x8 af[4], bfv[4];
#pragma unroll
    for (int i = 0; i < 4; ++i) af[i] = *(const s16x8*)&Al[wm + i * 16 + lr][lk];
#pragma unroll
    for (int j = 0; j < 4; ++j) bfv[j] = *(const s16x8*)&Bl[wn + j * 16 + lr][lk];
#pragma unroll
    for (int i = 0; i < 4; ++i)
#pragma unroll
      for (int j = 0; j < 4; ++j)
        acc[i][j] = __builtin_amdgcn_mfma_f32_16x16x32_bf16(bfv[j], af[i], acc[i][j], 0, 0, 0);
  }
#pragma unroll
  for (int i = 0; i < 4; ++i) {
    int M = m0 + wm + i * 16 + lr;
    int sgi = seg[M / 196];
    int hi = lane >> 4;
    const float* av = addv + (size_t)sgi * 768 + n0 + wn + hi * 4;
    float* orow = out + (size_t)M * 768 + n0 + wn + hi * 4;
#pragma unroll
    for (int j = 0; j < 4; ++j) {
      f32x4 a4 = *(const f32x4*)(av + j * 16);
      f32x4 v = acc[i][j];
      v.x += a4.x; v.y += a4.y; v.z += a4.z; v.w += a4.w;
      *(f32x4*)(orow + j * 16) = v;
    }
  }
}

// ---------------- launch ----------------

extern "C" void kernel_launch(void* const* d_in, const int* in_sizes, int n_in,
                              void* d_out, int out_size, void* d_ws, size_t ws_size,
                              hipStream_t stream) {
  (void)in_sizes; (void)n_in; (void)out_size;
  const float* x  = (const float*)d_in[0];
  const int*   sg = (const int*)d_in[1];
  const float* pw = (const float*)d_in[2];
  const float* pb = (const float*)d_in[3];
  const float* cw = (const float*)d_in[4];
  const float* cb = (const float*)d_in[5];
  float* out = (float*)d_out;

  char* ws = (char*)d_ws;
  unsigned short* pwbf = (unsigned short*)ws;            // 393216 B
  float* cwT   = (float*)(ws + 393216);                  // 2359296 B
  float* addv  = (float*)(ws + 2752512);                 // 98304 B
  float* means = (float*)(ws + 2850816);                 // 98304 B
  float* avg3  = (float*)(ws + 2949120);                 // 3670016 B
  unsigned short* xbf = (unsigned short*)(ws + 6619136); // 25690112 B
  const size_t NEED = 6619136u + 25690112u;              // 32.3 MB

  if (ws_size >= NEED) {
    k_mega<<<4352, 256, 0, stream>>>(x, xbf, avg3, pw, pwbf, cw, cwT);
    k_sm<<<32, 768, 0, stream>>>(avg3, sg, pw, pb, means);
    k_ctx2<<<768, 256, 0, stream>>>(means, cwT, cb, pb, addv);
    k_gemm<<<1176, 512, 0, stream>>>(xbf, pwbf, addv, sg, out);
  } else {
    float* avgp = (float*)(ws + 2949120);
    k_cvt_fb<<<192, 256, 0, stream>>>(pw, pwbf);
    k_transpose_fb<<<576, 256, 0, stream>>>(cw, cwT);
    k_avgpatch_fb<<<256, 256, 0, stream>>>(x, avgp);
    k_chain_fb<<<32, 768, 0, stream>>>(avgp, sg, pw, pb, cwT, cb, addv);
    k_gemm_fb<<<2352, 256, 0, stream>>>(x, pwbf, addv, sg, out);
  }
}

// Round 11
// 85.151 us; speedup vs baseline: 1.2021x; 1.2021x over previous
//
#include <hip/hip_runtime.h>
#include <hip/hip_bf16.h>

typedef __attribute__((ext_vector_type(8))) short s16x8;
typedef __attribute__((ext_vector_type(4))) float f32x4;
typedef __attribute__((ext_vector_type(8))) unsigned short u16x8;
typedef __attribute__((ext_vector_type(4))) unsigned short u16x4;

static __device__ __forceinline__ unsigned short f2bf(float f) {
  unsigned int u = __float_as_uint(f);
  unsigned int r = u + 0x7fffu + ((u >> 16) & 1u);
  return (unsigned short)(r >> 16);
}
static __device__ __forceinline__ float bf2f(unsigned short s) {
  return __uint_as_float(((unsigned int)s) << 16);
}

static __device__ __forceinline__ void gload16(const void* g, void* l) {
  __builtin_amdgcn_global_load_lds(
      (const __attribute__((address_space(1))) unsigned int*)g,
      (__attribute__((address_space(3))) unsigned int*)l, 16, 0, 0);
}

// ---------------- fused pre-pass (round-8 exact) ----------------
__global__ __launch_bounds__(256) void k_mega(const float* __restrict__ x,
                                              unsigned short* __restrict__ xbf,
                                              float* __restrict__ avg3,
                                              const float* __restrict__ pw,
                                              unsigned short* __restrict__ pwbf,
                                              const float* __restrict__ cw,
                                              float* __restrict__ cwT) {
  __shared__ __align__(16) char smem[14 * 272 * 2];  // 7616 B
  int b = blockIdx.x, t = threadIdx.x;
  if (b < 3584) {
    unsigned short* strip = (unsigned short*)smem;
    int bc = b / 14, hp = b - bc * 14;
    const float* img = x + ((size_t)bc * 224 + hp * 16) * 224;
    for (int idx = t; idx < 896; idx += 256) {
      int row = idx / 56, c4 = idx - row * 56;
      float4 v = reinterpret_cast<const float4*>(img + (size_t)row * 224)[c4];
      int wp = c4 >> 2, q0 = (c4 & 3) << 2;
      u16x4 pk = { f2bf(v.x), f2bf(v.y), f2bf(v.z), f2bf(v.w) };
      *(u16x4*)&strip[wp * 272 + row * 16 + q0] = pk;
    }
    __syncthreads();
    float acc = 0.f;
#pragma unroll
    for (int wp = 0; wp < 14; ++wp) acc += bf2f(strip[wp * 272 + t]);
    avg3[((size_t)bc * 14 + hp) * 256 + t] = acc;
    unsigned short* orow = xbf + ((size_t)bc * 196 + hp * 14) * 256;
    for (int i = t; i < 448; i += 256) {
      int patch = i >> 5, rem = i & 31;
      u16x8 v = *(const u16x8*)&strip[patch * 272 + (rem >> 1) * 16 + (rem & 1) * 8];
      *(u16x8*)(orow + i * 8) = v;
    }
  } else if (b < 3776) {
    int i = (b - 3584) * 256 + t;
    float4 v = reinterpret_cast<const float4*>(pw)[i];
    u16x4 pk = { f2bf(v.x), f2bf(v.y), f2bf(v.z), f2bf(v.w) };
    reinterpret_cast<u16x4*>(pwbf)[i] = pk;
  } else {
    float (*tile)[33] = (float(*)[33])smem;
    int bid2 = b - 3776;
    int bx = bid2 % 24, by = bid2 / 24;
    int tx = t & 31, ty = t >> 5;
#pragma unroll
    for (int k = 0; k < 4; ++k)
      tile[ty + 8 * k][tx] = cw[(size_t)(by * 32 + ty + 8 * k) * 768 + bx * 32 + tx];
    __syncthreads();
#pragma unroll
    for (int k = 0; k < 4; ++k)
      cwT[(size_t)(bx * 32 + ty + 8 * k) * 768 + by * 32 + tx] = tile[tx][ty + 8 * k];
  }
}

// ---------------- context chain (round-8 exact) ----------------
__global__ __launch_bounds__(256) void k_segmean(const float* __restrict__ avg3,
                                                 const int* __restrict__ seg,
                                                 float* __restrict__ sp) {
  __shared__ float red[4][64];
  __shared__ int rcnt[4];
  __shared__ int ssg[256];
  int s = blockIdx.x & 31, kc = blockIdx.x >> 5;
  int t = threadIdx.x;
  int kl = t & 63, slice = t >> 6;
  int k = kc * 64 + kl;
  ssg[t] = seg[t];
  __syncthreads();
  float sum = 0.f; int cnt = 0;
  for (int bc = slice * 64; bc < slice * 64 + 64; ++bc) {
    if (ssg[bc] == s) {
      ++cnt;
      const float* row = avg3 + (size_t)bc * 14 * 256 + k;
#pragma unroll
      for (int hp = 0; hp < 14; ++hp) sum += row[hp * 256];
    }
  }
  red[slice][kl] = sum;
  if (kl == 0) rcnt[slice] = cnt;
  __syncthreads();
  if (t < 64) {
    float tot = red[0][t] + red[1][t] + red[2][t] + red[3][t];
    int c = rcnt[0] + rcnt[1] + rcnt[2] + rcnt[3];
    sp[s * 256 + kc * 64 + t] = tot / (196.0f * (float)(c > 0 ? c : 1));
  }
}

__global__ __launch_bounds__(256) void k_means2(const float* __restrict__ sp,
                                                const float* __restrict__ pw,
                                                const float* __restrict__ pb,
                                                float* __restrict__ means) {
  __shared__ float ssp[256];
  __shared__ float red[8][32];
  int s = blockIdx.x & 31, e0 = (blockIdx.x >> 5) << 5;
  int t = threadIdx.x;
  int e = t & 31, ksl = t >> 5;
  ssp[t] = sp[s * 256 + t];
  __syncthreads();
  const float4* w = reinterpret_cast<const float4*>(pw + (size_t)(e0 + e) * 256 + ksl * 32);
  float a = 0.f;
#pragma unroll
  for (int j = 0; j < 8; ++j) {
    float4 v = w[j];
    int kb = ksl * 32 + j * 4;
    a += v.x * ssp[kb] + v.y * ssp[kb + 1] + v.z * ssp[kb + 2] + v.w * ssp[kb + 3];
  }
  red[ksl][e] = a;
  __syncthreads();
  if (t < 32) {
    float tot = 0.f;
#pragma unroll
    for (int j = 0; j < 8; ++j) tot += red[j][t];
    means[s * 768 + e0 + t] = tot + pb[e0 + t];
  }
}

__global__ __launch_bounds__(256) void k_ctx2(const float* __restrict__ means,
                                              const float* __restrict__ cwT,
                                              const float* __restrict__ cb,
                                              const float* __restrict__ pb,
                                              float* __restrict__ addv) {
  __shared__ float mn[768];
  __shared__ float red[8][32];
  int s = blockIdx.x & 31, e0 = (blockIdx.x >> 5) << 5;
  int t = threadIdx.x;
  int e = t & 31, fsl = t >> 5;
  mn[t] = means[s * 768 + t];
  mn[t + 256] = means[s * 768 + 256 + t];
  mn[t + 512] = means[s * 768 + 512 + t];
  __syncthreads();
  const float* col = cwT + (size_t)fsl * 96 * 768 + e0 + e;
  float a = 0.f;
#pragma unroll 8
  for (int j = 0; j < 96; ++j) a += mn[fsl * 96 + j] * col[(size_t)j * 768];
  red[fsl][e] = a;
  __syncthreads();
  if (t < 32) {
    float tot = 0.f;
#pragma unroll
    for (int j = 0; j < 8; ++j) tot += red[j][t];
    addv[s * 768 + e0 + t] = tot + cb[e0 + t] + pb[e0 + t];
  }
}

// ---------------- main GEMM (round-8 winner, exact) ----------------
// BM=128, BN=256, BK=64, 8 waves (2m x 4n), single-buffer, 2 barriers/tile.
// Swapped-operand MFMA -> lane holds 4 consecutive n -> dwordx4 epilogue.
__global__ __launch_bounds__(512) void k_gemm(
    const unsigned short* __restrict__ xbf, const unsigned short* __restrict__ wbf,
    const float* __restrict__ addv, const int* __restrict__ seg,
    float* __restrict__ out) {
  __shared__ __align__(16) unsigned short Al[128 * 64];  // 16 KB
  __shared__ __align__(16) unsigned short Bl[256 * 64];  // 32 KB

  // grid 1176 = 8 XCD x (49 mb x 3 nb)
  int bid = blockIdx.x;
  int xcd = bid & 7, local = bid >> 3;
  int mb = xcd * 49 + local / 3;
  int nb = local - (local / 3) * 3;
  int m0 = mb << 7, n0 = nb << 8;

  int t = threadIdx.x;
  int wave = t >> 6, lane = t & 63;
  int wm = (wave >> 2) << 6, wn = (wave & 3) << 6;
  int lr = lane & 15, hi = lane >> 4;
  int axor = (lr & 7) << 4;

  int swz = (((lane & 7) ^ ((lane >> 3) & 7)) << 4);
  const char* abase = (const char*)xbf + (size_t)(m0 + wave * 16 + (lane >> 3)) * 512 + swz;
  const char* bbase = (const char*)wbf + (size_t)(n0 + wave * 32 + (lane >> 3)) * 512 + swz;
  char* adst = (char*)Al + wave * 2048;
  char* bdst = (char*)Bl + wave * 4096;
  const char* Alc = (const char*)Al;
  const char* Blc = (const char*)Bl;

  f32x4 acc[4][4] = {};

  for (int kt = 0; kt < 4; ++kt) {
    __syncthreads();  // previous tile consumed
#pragma unroll
    for (int i = 0; i < 2; ++i)
      gload16(abase + kt * 128 + i * 4096, adst + i * 1024);
#pragma unroll
    for (int i = 0; i < 4; ++i)
      gload16(bbase + kt * 128 + i * 4096, bdst + i * 1024);
    __syncthreads();  // drains vmcnt + lgkm
#pragma unroll
    for (int kk = 0; kk < 2; ++kk) {
      s16x8 af[4], bv[4];
      int koff = kk * 64 + hi * 16;
#pragma unroll
      for (int i = 0; i < 4; ++i)
        af[i] = *(const s16x8*)(Alc + (wm + i * 16 + lr) * 128 + (koff ^ axor));
#pragma unroll
      for (int j = 0; j < 4; ++j)
        bv[j] = *(const s16x8*)(Blc + (wn + j * 16 + lr) * 128 + (koff ^ axor));
#pragma unroll
      for (int i = 0; i < 4; ++i)
#pragma unroll
        for (int j = 0; j < 4; ++j)
          acc[i][j] = __builtin_amdgcn_mfma_f32_16x16x32_bf16(bv[j], af[i], acc[i][j], 0, 0, 0);
    }
  }

  // epilogue: lane's acc[i][j] = C[m0+wm+i*16+lr][n0+wn+j*16+hi*4 .. +3]
#pragma unroll
  for (int i = 0; i < 4; ++i) {
    int M = m0 + wm + i * 16 + lr;
    int sgi = seg[M / 196];
    const float* av = addv + (size_t)sgi * 768 + n0 + wn + hi * 4;
    float* orow = out + (size_t)M * 768 + n0 + wn + hi * 4;
#pragma unroll
    for (int j = 0; j < 4; ++j) {
      f32x4 a4 = *(const f32x4*)(av + j * 16);
      f32x4 v = acc[i][j];
      v.x += a4.x; v.y += a4.y; v.z += a4.z; v.w += a4.w;
      *(f32x4*)(orow + j * 16) = v;
    }
  }
}

// ---------------- fallback path (if ws too small) ----------------
__global__ void k_cvt_fb(const float* __restrict__ in, unsigned short* __restrict__ o) {
  int i = blockIdx.x * 256 + threadIdx.x;
  float4 v = reinterpret_cast<const float4*>(in)[i];
  u16x4 pk = { f2bf(v.x), f2bf(v.y), f2bf(v.z), f2bf(v.w) };
  reinterpret_cast<u16x4*>(o)[i] = pk;
}

__global__ void k_transpose_fb(const float* __restrict__ in, float* __restrict__ out) {
  __shared__ float tile[32][33];
  int bx = blockIdx.x % 24, by = blockIdx.x / 24;
  int tx = threadIdx.x & 31, ty = threadIdx.x >> 5;
#pragma unroll
  for (int k = 0; k < 4; ++k)
    tile[ty + 8 * k][tx] = in[(size_t)(by * 32 + ty + 8 * k) * 768 + bx * 32 + tx];
  __syncthreads();
#pragma unroll
  for (int k = 0; k < 4; ++k)
    out[(size_t)(bx * 32 + ty + 8 * k) * 768 + by * 32 + tx] = tile[tx][ty + 8 * k];
}

__global__ void k_avgpatch_fb(const float* __restrict__ x, float* __restrict__ avg) {
  int bc = blockIdx.x;
  int k = threadIdx.x;
  int p = k >> 4, q = k & 15;
  const float* base = x + (size_t)bc * 224 * 224;
  float s = 0.f;
  for (int hp = 0; hp < 14; ++hp) {
    const float* row = base + (hp * 16 + p) * 224 + q;
#pragma unroll
    for (int wp = 0; wp < 14; ++wp) s += row[wp * 16];
  }
  avg[bc * 256 + k] = s * (1.0f / 196.0f);
}

__global__ __launch_bounds__(768) void k_chain_fb(const float* __restrict__ avg,
                                                  const int* __restrict__ seg,
                                                  const float* __restrict__ pw,
                                                  const float* __restrict__ pb,
                                                  const float* __restrict__ cwT,
                                                  const float* __restrict__ cb,
                                                  float* __restrict__ addv) {
  __shared__ float sp[256];
  __shared__ float mn[768];
  __shared__ int ssg[256];
  int s = blockIdx.x, t = threadIdx.x;
  if (t < 256) ssg[t] = seg[t];
  __syncthreads();
  if (t < 256) {
    float sum = 0.f; int c = 0;
    for (int bc = 0; bc < 256; ++bc)
      if (ssg[bc] == s) { sum += avg[bc * 256 + t]; ++c; }
    sp[t] = sum / (float)(c > 0 ? c : 1);
  }
  __syncthreads();
  {
    const float4* w = reinterpret_cast<const float4*>(pw + (size_t)t * 256);
    float a = 0.f;
#pragma unroll 8
    for (int k = 0; k < 64; ++k) {
      float4 v = w[k];
      a += v.x * sp[k * 4] + v.y * sp[k * 4 + 1] + v.z * sp[k * 4 + 2] + v.w * sp[k * 4 + 3];
    }
    mn[t] = a + pb[t];
  }
  __syncthreads();
  float a2 = 0.f;
#pragma unroll 8
  for (int f = 0; f < 768; ++f) a2 += mn[f] * cwT[(size_t)f * 768 + t];
  addv[s * 768 + t] = a2 + cb[t] + pb[t];
}

__global__ __launch_bounds__(256) void k_gemm_fb(
    const float* __restrict__ x, const unsigned short* __restrict__ wbf,
    const float* __restrict__ addv, const int* __restrict__ seg,
    float* __restrict__ out) {
  __shared__ unsigned short Al[128][40];
  __shared__ unsigned short Bl[128][40];
  int bid = blockIdx.x;
  int xcd = bid & 7, local = bid >> 3;
  int mb = xcd * 49 + local / 6;
  int nb = local - (local / 6) * 6;
  int m0 = mb << 7, n0 = nb << 7;
  int t = threadIdx.x;
  int wave = t >> 6, lane = t & 63;
  int wm = (wave >> 1) << 6, wn = (wave & 1) << 6;
  int lr = lane & 15, lk = (lane >> 4) << 3;
  int mstage = m0 + (t >> 1);
  int halfA = t & 1;
  int bc = mstage / 196;
  int pij = mstage - bc * 196;
  int hp = pij / 14;
  int wp = pij - hp * 14;
  const float* xbase = x + ((size_t)bc * 224 + hp * 16 + halfA) * 224 + wp * 16;
  const unsigned short* bsrc = wbf + (size_t)(n0 + (t >> 1)) * 256 + halfA * 16;
  unsigned short* adst = &Al[t >> 1][halfA * 16];
  unsigned short* bdst = &Bl[t >> 1][halfA * 16];
  f32x4 acc[4][4] = {};
  for (int ks = 0; ks < 8; ++ks) {
    __syncthreads();
    *(u16x8*)bdst       = *(const u16x8*)(bsrc + ks * 32);
    *(u16x8*)(bdst + 8) = *(const u16x8*)(bsrc + ks * 32 + 8);
    {
      const float4* src = reinterpret_cast<const float4*>(xbase + ks * 448);
      float4 v0 = src[0], v1 = src[1], v2 = src[2], v3 = src[3];
      u16x8 p0 = { f2bf(v0.x), f2bf(v0.y), f2bf(v0.z), f2bf(v0.w),
                   f2bf(v1.x), f2bf(v1.y), f2bf(v1.z), f2bf(v1.w) };
      u16x8 p1 = { f2bf(v2.x), f2bf(v2.y), f2bf(v2.z), f2bf(v2.w),
                   f2bf(v3.x), f2bf(v3.y), f2bf(v3.z), f2bf(v3.w) };
      *(u16x8*)adst = p0;
      *(u16x8*)(adst + 8) = p1;
    }
    __syncthreads();
    s16x8 af[4], bfv[4];
#pragma unroll
    for (int i = 0; i < 4; ++i) af[i] = *(const s16x8*)&Al[wm + i * 16 + lr][lk];
#pragma unroll
    for (int j = 0; j < 4; ++j) bfv[j] = *(const s16x8*)&Bl[wn + j * 16 + lr][lk];
#pragma unroll
    for (int i = 0; i < 4; ++i)
#pragma unroll
      for (int j = 0; j < 4; ++j)
        acc[i][j] = __builtin_amdgcn_mfma_f32_16x16x32_bf16(bfv[j], af[i], acc[i][j], 0, 0, 0);
  }
#pragma unroll
  for (int i = 0; i < 4; ++i) {
    int M = m0 + wm + i * 16 + lr;
    int sgi = seg[M / 196];
    int hi = lane >> 4;
    const float* av = addv + (size_t)sgi * 768 + n0 + wn + hi * 4;
    float* orow = out + (size_t)M * 768 + n0 + wn + hi * 4;
#pragma unroll
    for (int j = 0; j < 4; ++j) {
      f32x4 a4 = *(const f32x4*)(av + j * 16);
      f32x4 v = acc[i][j];
      v.x += a4.x; v.y += a4.y; v.z += a4.z; v.w += a4.w;
      *(f32x4*)(orow + j * 16) = v;
    }
  }
}

// ---------------- launch ----------------

extern "C" void kernel_launch(void* const* d_in, const int* in_sizes, int n_in,
                              void* d_out, int out_size, void* d_ws, size_t ws_size,
                              hipStream_t stream) {
  (void)in_sizes; (void)n_in; (void)out_size;
  const float* x  = (const float*)d_in[0];
  const int*   sg = (const int*)d_in[1];
  const float* pw = (const float*)d_in[2];
  const float* pb = (const float*)d_in[3];
  const float* cw = (const float*)d_in[4];
  const float* cb = (const float*)d_in[5];
  float* out = (float*)d_out;

  char* ws = (char*)d_ws;
  unsigned short* pwbf = (unsigned short*)ws;            // 393216 B
  float* cwT   = (float*)(ws + 393216);                  // 2359296 B
  float* addv  = (float*)(ws + 2752512);                 // 98304 B
  float* sp    = (float*)(ws + 2850816);                 // 32768 B
  float* means = (float*)(ws + 2883584);                 // 98304 B
  float* avg3  = (float*)(ws + 2981888);                 // 3670016 B
  unsigned short* xbf = (unsigned short*)(ws + 6651904); // 25690112 B
  const size_t NEED = 6651904u + 25690112u;              // 32.3 MB

  if (ws_size >= NEED) {
    k_mega<<<4352, 256, 0, stream>>>(x, xbf, avg3, pw, pwbf, cw, cwT);
    k_segmean<<<128, 256, 0, stream>>>(avg3, sg, sp);
    k_means2<<<768, 256, 0, stream>>>(sp, pw, pb, means);
    k_ctx2<<<768, 256, 0, stream>>>(means, cwT, cb, pb, addv);
    k_gemm<<<1176, 512, 0, stream>>>(xbf, pwbf, addv, sg, out);
  } else {
    float* avgp = (float*)(ws + 2981888);
    k_cvt_fb<<<192, 256, 0, stream>>>(pw, pwbf);
    k_transpose_fb<<<576, 256, 0, stream>>>(cw, cwT);
    k_avgpatch_fb<<<256, 256, 0, stream>>>(x, avgp);
    k_chain_fb<<<32, 768, 0, stream>>>(avgp, sg, pw, pb, cwT, cb, addv);
    k_gemm_fb<<<2352, 256, 0, stream>>>(x, pwbf, addv, sg, out);
  }
}